// Round 13
// baseline (631.068 us; speedup 1.0000x reference)
//
#include <hip/hip_runtime.h>
#include <hip/hip_bf16.h>

// ---------------------------------------------------------------------------
// KV-cached MHA, MI355X. Round 13 (base = round 11; r12 copy-fusion reverted):
//  * prep (with cache copy + bf16 mirrors), gemm8, launch config: R11 VERBATIM.
//  * attn_k: r11 staging (K gload_lds DMA, V 2-way swizzle, V reg prefetch)
//    + T13 defer-rescale (r12, passed)
//    + NEW: l via ones-column MFMA — l = P·1 computed by one extra
//      MFMA16(pf, ones, accL) per trip; accL rescaled by alpha alongside
//      accO. Removes the 16 sum-shuffles + adds per trip (~half the serial
//      softmax chain). Denominator now from the same bf16-rounded P as the
//      numerator (more self-consistent).
// ---------------------------------------------------------------------------

typedef __bf16 bf16x8 __attribute__((ext_vector_type(8)));
typedef unsigned short u16x8 __attribute__((ext_vector_type(8)));
typedef float  f32x4  __attribute__((ext_vector_type(4)));
typedef unsigned int u32;

#define MFMA16(a, b, c) __builtin_amdgcn_mfma_f32_16x16x32_bf16((a), (b), (c), 0, 0, 0)

__device__ __forceinline__ void async16(__bf16* lds_p, const __bf16* g) {
    __builtin_amdgcn_global_load_lds(
        (__attribute__((address_space(1))) void*)g,
        (__attribute__((address_space(3))) void*)lds_p, 16, 0, 0);
}

// ---------------------------------------------------------------------------
// prep: one grid-stride BW pass (r8/r11 verbatim: cache copy + mirrors + cvt).
// ---------------------------------------------------------------------------
__global__ __launch_bounds__(256) void prep(
    const float* __restrict__ q, const float* __restrict__ k, const float* __restrict__ v,
    const float* __restrict__ wq, const float* __restrict__ wk,
    const float* __restrict__ wv, const float* __restrict__ wo,
    const float* __restrict__ ck, const float* __restrict__ cv,
    float* __restrict__ nk, float* __restrict__ nv,
    __bf16* __restrict__ dq, __bf16* __restrict__ dk, __bf16* __restrict__ dv,
    __bf16* __restrict__ dwq, __bf16* __restrict__ dwk,
    __bf16* __restrict__ dwv, __bf16* __restrict__ dwo,
    __bf16* __restrict__ ckb, __bf16* __restrict__ cvb) {
    const int nthreads = gridDim.x * blockDim.x;
    for (int i = blockIdx.x * blockDim.x + threadIdx.x; i < 7340032; i += nthreads) {
        if (i < 2097152) {
            const int sel = i >> 20;
            const int j = i & 1048575;
            const int dh8 = j & 15;
            const int t = (j >> 4) & 1023;
            const int h = (j >> 14) & 15;
            const int b = j >> 18;
            const float* src = sel ? cv : ck;
            float* dst = sel ? nv : nk;
            __bf16* dstb = sel ? cvb : ckb;
            const size_t si = ((size_t)(b << 10) + t) * 2048 + (h << 7) + (dh8 << 3);
            const size_t di = ((size_t)b << 22) + ((size_t)h << 18) + (t << 7) + (dh8 << 3);
            const size_t bi = (((size_t)(b * 16 + h) * 1024 + t) << 7) + (dh8 << 3);
            const f32x4 x0 = *(const f32x4*)&src[si];
            const f32x4 x1 = *(const f32x4*)&src[si + 4];
            *(f32x4*)&dst[di] = x0;
            *(f32x4*)&dst[di + 4] = x1;
            bf16x8 bx;
#pragma unroll
            for (int e = 0; e < 4; e++) {
                bx[e]     = (__bf16)x0[e];
                bx[e + 4] = (__bf16)x1[e];
            }
            *(bf16x8*)&dstb[bi] = bx;
        } else {
            const float* s;
            __bf16* d;
            int off;
            if (i < 5242880) {
                const int ii = i - 2097152;
                const int r = ii >> 20;
                off = ii & 1048575;
                s = (r == 0) ? q : (r == 1) ? k : v;
                d = (r == 0) ? dq : (r == 1) ? dk : dv;
            } else {
                const int ii = i - 5242880;
                const int r = ii >> 19;
                off = ii & 524287;
                s = (r == 0) ? wq : (r == 1) ? wk : (r == 2) ? wv : wo;
                d = (r == 0) ? dwq : (r == 1) ? dwk : (r == 2) ? dwv : dwo;
            }
            const f32x4 x0 = *(const f32x4*)(s + (size_t)off * 8);
            const f32x4 x1 = *(const f32x4*)(s + (size_t)off * 8 + 4);
            bf16x8 o;
#pragma unroll
            for (int j2 = 0; j2 < 4; j2++) {
                o[j2]     = (__bf16)x0[j2];
                o[j2 + 4] = (__bf16)x1[j2];
            }
            *(bf16x8*)(d + (size_t)off * 8) = o;
        }
    }
}

// ---------------------------------------------------------------------------
// 128x256 8-phase GEMM (round-4/8/11 verbatim; best measured GEMM config).
// ---------------------------------------------------------------------------
template <int MODE>
__global__ __launch_bounds__(512, 2) void gemm8(
    const __bf16* __restrict__ A,
    const __bf16* __restrict__ W0, const __bf16* __restrict__ W1,
    const __bf16* __restrict__ W2,
    const float* __restrict__ bz0, const float* __restrict__ bz1,
    const float* __restrict__ bz2,
    void* __restrict__ C0, float* __restrict__ C1, float* __restrict__ C2) {
    extern __shared__ __bf16 lds[];
    constexpr int K = 2048;
    const int tid = threadIdx.x;
    const int w = tid >> 6, lane = tid & 63;
    const int wm = w >> 2, wn = w & 3;
    const int g = lane >> 4, c = lane & 15;

    const int lin = blockIdx.x;
    const int nb = lin & 7, mb = lin >> 3;
    const int m0 = mb << 7, n0 = nb << 8;
    const int seg = (MODE == 1) ? (mb >> 5) : 0;
    const __bf16* W = (MODE == 0 || seg == 0) ? W0 : (seg == 1) ? W1 : W2;
    const float* bias = (MODE == 0) ? bz0 : (seg == 0) ? bz0 : (seg == 1) ? bz1 : bz2;

    const __bf16* Ab = A + (size_t)m0 * K;
    const __bf16* Wb = W + (size_t)n0 * K;

    const int srow = lane >> 2;
    const int sch = (lane & 3) ^ (((lane >> 5) & 1) << 1);
    const int foff = c * 32 + ((g ^ ((c >> 3) << 1)) << 3);

    f32x4 acc[4][4] = {};

    auto stgA = [&](int T, int rg) {
#pragma unroll
        for (int u = 0; u < 2; u++) {
            const __bf16* gs = Ab + (size_t)(w * 16 + srow) * K + T * 64 + u * 32 + sch * 8;
            async16(&lds[rg * 24576 + (w * 2 + u) * 512], gs);
        }
    };
    auto stgB = [&](int T, int rg) {
#pragma unroll
        for (int u = 0; u < 4; u++) {
            const int rowblk = 2 * w + (u >> 1), kk = u & 1;
            const __bf16* gs = Wb + (size_t)(rowblk * 16 + srow) * K + T * 64 + kk * 32 + sch * 8;
            async16(&lds[rg * 24576 + 8192 + (w * 4 + u) * 512], gs);
        }
    };

    stgA(0, 0); stgB(0, 0);
    stgA(1, 1); stgB(1, 1);
    asm volatile("s_waitcnt vmcnt(6)" ::: "memory");
    asm volatile("s_barrier" ::: "memory");

    int rg = 0;
    for (int T = 0; T < 32; T++) {
        int rs = rg + 2; if (rs >= 3) rs -= 3;
        const int base = rg * 24576;
        bf16x8 fa[4], fb[4];

#pragma unroll
        for (int mi = 0; mi < 4; mi++)
            fa[mi] = *(const bf16x8*)&lds[base + ((wm * 4 + mi) * 2 + 0) * 512 + foff];
#pragma unroll
        for (int ni = 0; ni < 4; ni++)
            fb[ni] = *(const bf16x8*)&lds[base + 8192 + ((wn * 4 + ni) * 2 + 0) * 512 + foff];
        if (T < 30) stgA(T + 2, rs);
        asm volatile("s_barrier" ::: "memory");
        asm volatile("s_waitcnt lgkmcnt(0)" ::: "memory");
        __builtin_amdgcn_sched_barrier(0);
        __builtin_amdgcn_s_setprio(1);
#pragma unroll
        for (int mi = 0; mi < 4; mi++)
#pragma unroll
            for (int ni = 0; ni < 4; ni++)
                acc[mi][ni] = MFMA16(fa[mi], fb[ni], acc[mi][ni]);
        __builtin_amdgcn_s_setprio(0);
        asm volatile("s_barrier" ::: "memory");

#pragma unroll
        for (int mi = 0; mi < 4; mi++)
            fa[mi] = *(const bf16x8*)&lds[base + ((wm * 4 + mi) * 2 + 1) * 512 + foff];
#pragma unroll
        for (int ni = 0; ni < 4; ni++)
            fb[ni] = *(const bf16x8*)&lds[base + 8192 + ((wn * 4 + ni) * 2 + 1) * 512 + foff];
        if (T < 30) {
            stgB(T + 2, rs);
            asm volatile("s_waitcnt vmcnt(6)" ::: "memory");
        } else {
            asm volatile("s_waitcnt vmcnt(0)" ::: "memory");
        }
        asm volatile("s_barrier" ::: "memory");
        asm volatile("s_waitcnt lgkmcnt(0)" ::: "memory");
        __builtin_amdgcn_sched_barrier(0);
        __builtin_amdgcn_s_setprio(1);
#pragma unroll
        for (int mi = 0; mi < 4; mi++)
#pragma unroll
            for (int ni = 0; ni < 4; ni++)
                acc[mi][ni] = MFMA16(fa[mi], fb[ni], acc[mi][ni]);
        __builtin_amdgcn_s_setprio(0);
        asm volatile("s_barrier" ::: "memory");

        rg = (rg + 1 == 3) ? 0 : rg + 1;
    }

#pragma unroll
    for (int ni = 0; ni < 4; ni++) {
        const int col = n0 + wn * 64 + ni * 16 + c;
        const float bv = bias[col];
        const int h = col >> 7, dh = col & 127;
#pragma unroll
        for (int mi = 0; mi < 4; mi++) {
            const int rowb = m0 + wm * 64 + mi * 16 + g * 4;
#pragma unroll
            for (int r = 0; r < 4; r++) {
                const float v = acc[mi][ni][r] + bv;
                if (MODE == 0) {
                    ((float*)C0)[(size_t)(rowb + r) * 2048 + col] = v;
                } else {
                    const int lrow = (rowb + r) & 4095;
                    const int b = lrow >> 10, t = lrow & 1023;
                    if (seg == 0)
                        ((__bf16*)C0)[(((size_t)(b * 16 + h) * 1024) + t) * 128 + dh] = (__bf16)v;
                    else if (seg == 1)
                        C1[(((size_t)(b * 16 + h) * 2048) + 1024 + t) * 128 + dh] = v;
                    else
                        C2[(((size_t)(b * 16 + h) * 2048) + 1024 + t) * 128 + dh] = v;
                }
            }
        }
    }
}

// ---------------------------------------------------------------------------
// Flash attention (r11 staging verbatim) + T13 defer-rescale + l-via-MFMA.
// QBLK=32, 2-wave 128-thread blocks, 2048 blocks = 8/CU; bijective balanced
// qb map; 8 heads/XCD. K via global_load_lds (4 calls/wave of 4 rows,
// pre-swizzled source); V 2-way-swizzled u32 key-pairs + next-trip register
// prefetch. l computed as P·1 by one extra MFMA per trip (accL), rescaled
// with accO; the per-trip sum-shuffle tree is eliminated.
// ---------------------------------------------------------------------------
__global__ __launch_bounds__(128) void attn_k(const __bf16* __restrict__ Qw,
                                              const __bf16* __restrict__ cK,
                                              const __bf16* __restrict__ cV,
                                              __bf16* __restrict__ O) {
    __shared__ __bf16 Kt[32 * 128];     // 8 KB
    __shared__ u32 Vt32[128 * 16];      // 8 KB
    __shared__ __bf16 Pw[2][16 * 32];   // 2 KB

    const int tid = threadIdx.x;
    const int w = tid >> 6;             // 0..1
    const int lane = tid & 63;
    const int g = lane >> 4, c = lane & 15;

    const int lin = blockIdx.x + (blockIdx.y << 4) + (blockIdx.z << 8);
    const int xcd = lin & 7;
    const int j = lin >> 3;
    const int bh = xcd * 8 + (j & 7);
    const int qq = j >> 3;              // 0..31
    const int c4 = qq & 3, mq = qq >> 2;
    const int qb = ((mq & 1) == 0) ? (c4 * 4 + (mq >> 1)) : (31 - c4 * 4 - (mq >> 1));
    const int b = bh >> 4, h = bh & 15;
    const int q0 = qb << 5;
    const float inv_scale = 0.08838834764831845f; // 1/sqrt(128)

    const __bf16* qbase = Qw + (((size_t)bh * 1024) + q0 + w * 16) * 128;
    bf16x8 qf[4];
#pragma unroll
    for (int dc = 0; dc < 4; dc++)
        qf[dc] = *(const bf16x8*)&qbase[c * 128 + dc * 32 + g * 8];

    bf16x8 ones;
#pragma unroll
    for (int i = 0; i < 8; i++) ones[i] = (__bf16)1.0f;

    f32x4 accO[8] = {};
    f32x4 accL = {};
    float m_run[4];
#pragma unroll
    for (int r = 0; r < 4; r++) m_run[r] = -1e30f;

    const int trips = qb + 1;
    const __bf16* kb = cK + (size_t)bh * 1024 * 128;
    const __bf16* vb = cV + (size_t)bh * 1024 * 128;

    // K DMA map (r2-verified geometry): 4 calls/wave of 4 rows each.
    size_t ksrc[4];
    __bf16* kdst[4];
#pragma unroll
    for (int j2 = 0; j2 < 4; j2++) {
        const int keyb = w * 16 + j2 * 4;
        const int row = keyb + (lane >> 4);
        ksrc[j2] = (size_t)row * 128 + (((lane & 15) ^ (row & 7)) << 3);
        kdst[j2] = &Kt[keyb * 128];
    }

    // V staging: thread owns key pair kp=tid>>3, dh block dbv=tid&7 (16 dh)
    const int kp = tid >> 3, dbv = tid & 7;
    const __bf16* vbase = vb + (size_t)(2 * kp) * 128 + dbv * 16;

    bf16x8 v0a = *(const bf16x8*)&vbase[0];
    bf16x8 v0b = *(const bf16x8*)&vbase[8];
    bf16x8 v1a = *(const bf16x8*)&vbase[128];
    bf16x8 v1b = *(const bf16x8*)&vbase[136];

    for (int kt = 0; kt < trips; kt++) {
        const int k0 = kt * 32;
        __syncthreads();   // #1: prior trip's Kt/Vt reads complete
#pragma unroll
        for (int j2 = 0; j2 < 4; j2++)
            async16(kdst[j2], kb + (size_t)k0 * 128 + ksrc[j2]);
        {
            const u16x8 a0 = __builtin_bit_cast(u16x8, v0a);
            const u16x8 a1 = __builtin_bit_cast(u16x8, v0b);
            const u16x8 b0 = __builtin_bit_cast(u16x8, v1a);
            const u16x8 b1 = __builtin_bit_cast(u16x8, v1b);
#pragma unroll
            for (int jj = 0; jj < 8; jj++) {
                const int d0 = dbv * 16 + jj;
                const int d1 = d0 + 8;
                const int h0 = ((d0 >> 4) ^ (d0 >> 2)) & 3;
                const int h1 = ((d1 >> 4) ^ (d1 >> 2)) & 3;
                const int col0 = (((kp >> 2) ^ h0) << 2) | (kp & 3);
                const int col1 = (((kp >> 2) ^ h1) << 2) | (kp & 3);
                Vt32[d0 * 16 + col0] = (u32)a0[jj] | ((u32)b0[jj] << 16);
                Vt32[d1 * 16 + col1] = (u32)a1[jj] | ((u32)b1[jj] << 16);
            }
        }
        __syncthreads();   // #2: K DMA + V writes visible

        const bool more = (kt + 1 < trips);
        bf16x8 n0a = {}, n0b = {}, n1a = {}, n1b = {};
        if (more) {
            const __bf16* vn = vbase + (size_t)(k0 + 32) * 128;
            n0a = *(const bf16x8*)&vn[0];
            n0b = *(const bf16x8*)&vn[8];
            n1a = *(const bf16x8*)&vn[128];
            n1b = *(const bf16x8*)&vn[136];
        }

        // S = Q @ K^T  (two 16-key tiles)
        f32x4 s_acc[2] = {};
#pragma unroll
        for (int nt = 0; nt < 2; nt++) {
            const int krow = nt * 16 + c;
            const int ks = krow & 7;
#pragma unroll
            for (int dc = 0; dc < 4; dc++) {
                const bf16x8 kf =
                    *(const bf16x8*)&Kt[krow * 128 + (((dc * 4 + g) ^ ks) << 3)];
                s_acc[nt] = MFMA16(qf[dc], kf, s_acc[nt]);
            }
        }

        // pass 1: masked scores + row maxes (max-shuffle tree only)
        float sv0[4], sv1[4], rmax[4];
#pragma unroll
        for (int r = 0; r < 4; r++) {
            const int qrow = q0 + w * 16 + g * 4 + r;
            sv0[r] = (k0 + c      <= qrow) ? s_acc[0][r] * inv_scale : -1e30f;
            sv1[r] = (k0 + 16 + c <= qrow) ? s_acc[1][r] * inv_scale : -1e30f;
            float rm = fmaxf(sv0[r], sv1[r]);
            rm = fmaxf(rm, __shfl_xor(rm, 1));
            rm = fmaxf(rm, __shfl_xor(rm, 2));
            rm = fmaxf(rm, __shfl_xor(rm, 4));
            rm = fmaxf(rm, __shfl_xor(rm, 8));
            rmax[r] = rm;
        }
        // T13 defer-rescale: wave-uniform skip when no row grew by > 8
        int grow = 0;
#pragma unroll
        for (int r = 0; r < 4; r++)
            grow |= (rmax[r] > m_run[r] + 8.0f) ? 1 : 0;
        const bool rescale = (bool)__any(grow);

        // pass 2: exp only (no sum shuffles — l comes from P·1 MFMA)
        float p[2][4];
        if (rescale) {
            float alpha[4];
#pragma unroll
            for (int r = 0; r < 4; r++) {
                const float mnew = fmaxf(m_run[r], rmax[r]);
                alpha[r] = __expf(m_run[r] - mnew);
                p[0][r] = __expf(sv0[r] - mnew);
                p[1][r] = __expf(sv1[r] - mnew);
                m_run[r] = mnew;
            }
#pragma unroll
            for (int nt2 = 0; nt2 < 8; nt2++)
#pragma unroll
                for (int r = 0; r < 4; r++)
                    accO[nt2][r] *= alpha[r];
#pragma unroll
            for (int r = 0; r < 4; r++)
                accL[r] *= alpha[r];
        } else {
#pragma unroll
            for (int r = 0; r < 4; r++) {
                p[0][r] = __expf(sv0[r] - m_run[r]);
                p[1][r] = __expf(sv1[r] - m_run[r]);
            }
        }

        // P -> per-wave LDS (swizzled)
#pragma unroll
        for (int nt = 0; nt < 2; nt++)
#pragma unroll
            for (int r = 0; r < 4; r++)
                Pw[w][(g * 4 + r) * 32 + ((((nt << 1) | (c >> 3)) ^ g) << 3) + (c & 7)] =
                    (__bf16)p[nt][r];
        asm volatile("s_waitcnt lgkmcnt(0)" ::: "memory");
        __builtin_amdgcn_sched_barrier(0);

        const bf16x8 pf = *(const bf16x8*)&Pw[w][c * 32 + ((g ^ ((c >> 2) & 3)) << 3)];
        accL = MFMA16(pf, ones, accL);   // l += P·1 (row-sum, same in all cols)
#pragma unroll
        for (int nt2 = 0; nt2 < 8; nt2++) {
            const int vrow = nt2 * 16 + c;
            const int hv = ((vrow >> 4) ^ (vrow >> 2)) & 3;
            const bf16x8 vf = *(const bf16x8*)&(
                (const __bf16*)Vt32)[vrow * 32 + ((g ^ hv) << 3)];
            accO[nt2] = MFMA16(pf, vf, accO[nt2]);
        }

        if (more) { v0a = n0a; v0b = n0b; v1a = n1a; v1b = n1b; }
    }

    // epilogue: normalize by accL (row-sum, identical across cols), store bf16
#pragma unroll
    for (int nt2 = 0; nt2 < 8; nt2++)
#pragma unroll
        for (int r = 0; r < 4; r++) {
            const float v = accO[nt2][r] / accL[r];
            const int row = b * 1024 + q0 + w * 16 + g * 4 + r;
            const int col = h * 128 + nt2 * 16 + c;
            O[(size_t)row * 2048 + col] = (__bf16)v;
        }
}

// ---------------------------------------------------------------------------
extern "C" void kernel_launch(void* const* d_in, const int* in_sizes, int n_in,
                              void* d_out, int out_size, void* d_ws, size_t ws_size,
                              hipStream_t stream) {
    const float* query       = (const float*)d_in[0];
    const float* key         = (const float*)d_in[1];
    const float* value       = (const float*)d_in[2];
    const float* cache_key   = (const float*)d_in[3];
    const float* cache_value = (const float*)d_in[4];
    const float* Wq = (const float*)d_in[5];
    const float* bq = (const float*)d_in[6];
    const float* Wk = (const float*)d_in[7];
    const float* bk = (const float*)d_in[8];
    const float* Wv = (const float*)d_in[9];
    const float* bv = (const float*)d_in[10];
    const float* Wo = (const float*)d_in[11];
    const float* bo = (const float*)d_in[12];

    float* out   = (float*)d_out;              // [4096][2048] fp32
    float* new_k = out + 8388608;              // [B][H][2048][128] fp32
    float* new_v = out + 25165824;

    // workspace (bf16 elems): q_bf/k_bf/v_bf MUST be contiguous (A-concat)
    __bf16* p = (__bf16*)d_ws;
    __bf16* ws_q    = p; p += 8388608;         // [b][h][1024][128]
    __bf16* ws_attn = p; p += 8388608;         // [4096][2048]
    __bf16* q_bf    = p; p += 8388608;         // A-concat rows 0..4095
    __bf16* k_bf    = p; p += 8388608;         //               4096..8191
    __bf16* v_bf    = p; p += 8388608;         //               8192..12287
    __bf16* wq_bf   = p; p += 4194304;
    __bf16* wk_bf   = p; p += 4194304;
    __bf16* wv_bf   = p; p += 4194304;
    __bf16* wo_bf   = p; p += 4194304;
    __bf16* ck_bf   = p; p += 8388608;         // [b][h][1024][128] head-major
    __bf16* cv_bf   = p;

    static bool s_attr = false;
    if (!s_attr) {
        hipFuncSetAttribute(reinterpret_cast<const void*>(&gemm8<1>),
                            hipFuncAttributeMaxDynamicSharedMemorySize, 147456);
        hipFuncSetAttribute(reinterpret_cast<const void*>(&gemm8<0>),
                            hipFuncAttributeMaxDynamicSharedMemorySize, 147456);
        s_attr = true;
    }

    prep<<<4096, 256, 0, stream>>>(query, key, value, Wq, Wk, Wv, Wo,
                                   cache_key, cache_value, new_k, new_v,
                                   q_bf, k_bf, v_bf, wq_bf, wk_bf, wv_bf, wo_bf,
                                   ck_bf, cv_bf);
    gemm8<1><<<768, 512, 147456, stream>>>(q_bf, wq_bf, wk_bf, wv_bf,
                                           bq, bk, bv, ws_q, new_k, new_v);
    attn_k<<<dim3(16, 16, 8), 128, 0, stream>>>(ws_q, ck_bf, cv_bf, ws_attn);
    gemm8<0><<<256, 512, 147456, stream>>>(ws_attn, wo_bf, nullptr, nullptr,
                                           bo, nullptr, nullptr, out, nullptr, nullptr);
}

// Round 14
// 620.174 us; speedup vs baseline: 1.0176x; 1.0176x over previous
//
#include <hip/hip_runtime.h>
#include <hip/hip_bf16.h>

// ---------------------------------------------------------------------------
// KV-cached MHA, MI355X. Round 14 = ROUND 8 VERBATIM (best measured: 615.6us).
// Session lock-in: r9-r13 attempts (counted-vmcnt depth, attn DMA staging,
// copy-fusion, T13, l-via-MFMA) all landed within the +/-6% noise band or
// regressed; r8 is the best verified configuration.
//  * prep: fused cache copy (fp32 + bf16 head-major mirrors) + q/k/v/W cvt.
//  * gemm8: 128x256 8-phase, ring-of-3 LDS, counted vmcnt(6), setprio,
//    qkv fused 768 blocks (3 exact rounds), out-proj 256 blocks (1 round).
//  * attn_k: QBLK=32, 2-wave 128-thr blocks, 2048 blocks = 8/CU, bijective
//    balanced qb map (per-CU trip sum 132), 8 heads/XCD (L2-resident K/V).
// ---------------------------------------------------------------------------

typedef __bf16 bf16x8 __attribute__((ext_vector_type(8)));
typedef unsigned short u16x8 __attribute__((ext_vector_type(8)));
typedef float  f32x4  __attribute__((ext_vector_type(4)));
typedef unsigned int u32;

#define MFMA16(a, b, c) __builtin_amdgcn_mfma_f32_16x16x32_bf16((a), (b), (c), 0, 0, 0)

__device__ __forceinline__ void async16(__bf16* lds_p, const __bf16* g) {
    __builtin_amdgcn_global_load_lds(
        (__attribute__((address_space(1))) void*)g,
        (__attribute__((address_space(3))) void*)lds_p, 16, 0, 0);
}

// ---------------------------------------------------------------------------
// prep: one grid-stride BW pass.
// ---------------------------------------------------------------------------
__global__ __launch_bounds__(256) void prep(
    const float* __restrict__ q, const float* __restrict__ k, const float* __restrict__ v,
    const float* __restrict__ wq, const float* __restrict__ wk,
    const float* __restrict__ wv, const float* __restrict__ wo,
    const float* __restrict__ ck, const float* __restrict__ cv,
    float* __restrict__ nk, float* __restrict__ nv,
    __bf16* __restrict__ dq, __bf16* __restrict__ dk, __bf16* __restrict__ dv,
    __bf16* __restrict__ dwq, __bf16* __restrict__ dwk,
    __bf16* __restrict__ dwv, __bf16* __restrict__ dwo,
    __bf16* __restrict__ ckb, __bf16* __restrict__ cvb) {
    const int nthreads = gridDim.x * blockDim.x;
    for (int i = blockIdx.x * blockDim.x + threadIdx.x; i < 7340032; i += nthreads) {
        if (i < 2097152) {
            const int sel = i >> 20;
            const int j = i & 1048575;
            const int dh8 = j & 15;
            const int t = (j >> 4) & 1023;
            const int h = (j >> 14) & 15;
            const int b = j >> 18;
            const float* src = sel ? cv : ck;
            float* dst = sel ? nv : nk;
            __bf16* dstb = sel ? cvb : ckb;
            const size_t si = ((size_t)(b << 10) + t) * 2048 + (h << 7) + (dh8 << 3);
            const size_t di = ((size_t)b << 22) + ((size_t)h << 18) + (t << 7) + (dh8 << 3);
            const size_t bi = (((size_t)(b * 16 + h) * 1024 + t) << 7) + (dh8 << 3);
            const f32x4 x0 = *(const f32x4*)&src[si];
            const f32x4 x1 = *(const f32x4*)&src[si + 4];
            *(f32x4*)&dst[di] = x0;
            *(f32x4*)&dst[di + 4] = x1;
            bf16x8 bx;
#pragma unroll
            for (int e = 0; e < 4; e++) {
                bx[e]     = (__bf16)x0[e];
                bx[e + 4] = (__bf16)x1[e];
            }
            *(bf16x8*)&dstb[bi] = bx;
        } else {
            const float* s;
            __bf16* d;
            int off;
            if (i < 5242880) {
                const int ii = i - 2097152;
                const int r = ii >> 20;
                off = ii & 1048575;
                s = (r == 0) ? q : (r == 1) ? k : v;
                d = (r == 0) ? dq : (r == 1) ? dk : dv;
            } else {
                const int ii = i - 5242880;
                const int r = ii >> 19;
                off = ii & 524287;
                s = (r == 0) ? wq : (r == 1) ? wk : (r == 2) ? wv : wo;
                d = (r == 0) ? dwq : (r == 1) ? dwk : (r == 2) ? dwv : dwo;
            }
            const f32x4 x0 = *(const f32x4*)(s + (size_t)off * 8);
            const f32x4 x1 = *(const f32x4*)(s + (size_t)off * 8 + 4);
            bf16x8 o;
#pragma unroll
            for (int j2 = 0; j2 < 4; j2++) {
                o[j2]     = (__bf16)x0[j2];
                o[j2 + 4] = (__bf16)x1[j2];
            }
            *(bf16x8*)(d + (size_t)off * 8) = o;
        }
    }
}

// ---------------------------------------------------------------------------
// 128x256 8-phase GEMM (round-4 structure; best measured GEMM config).
// ---------------------------------------------------------------------------
template <int MODE>
__global__ __launch_bounds__(512, 2) void gemm8(
    const __bf16* __restrict__ A,
    const __bf16* __restrict__ W0, const __bf16* __restrict__ W1,
    const __bf16* __restrict__ W2,
    const float* __restrict__ bz0, const float* __restrict__ bz1,
    const float* __restrict__ bz2,
    void* __restrict__ C0, float* __restrict__ C1, float* __restrict__ C2) {
    extern __shared__ __bf16 lds[];
    constexpr int K = 2048;
    const int tid = threadIdx.x;
    const int w = tid >> 6, lane = tid & 63;
    const int wm = w >> 2, wn = w & 3;
    const int g = lane >> 4, c = lane & 15;

    const int lin = blockIdx.x;
    const int nb = lin & 7, mb = lin >> 3;
    const int m0 = mb << 7, n0 = nb << 8;
    const int seg = (MODE == 1) ? (mb >> 5) : 0;
    const __bf16* W = (MODE == 0 || seg == 0) ? W0 : (seg == 1) ? W1 : W2;
    const float* bias = (MODE == 0) ? bz0 : (seg == 0) ? bz0 : (seg == 1) ? bz1 : bz2;

    const __bf16* Ab = A + (size_t)m0 * K;
    const __bf16* Wb = W + (size_t)n0 * K;

    const int srow = lane >> 2;
    const int sch = (lane & 3) ^ (((lane >> 5) & 1) << 1);
    const int foff = c * 32 + ((g ^ ((c >> 3) << 1)) << 3);

    f32x4 acc[4][4] = {};

    auto stgA = [&](int T, int rg) {
#pragma unroll
        for (int u = 0; u < 2; u++) {
            const __bf16* gs = Ab + (size_t)(w * 16 + srow) * K + T * 64 + u * 32 + sch * 8;
            async16(&lds[rg * 24576 + (w * 2 + u) * 512], gs);
        }
    };
    auto stgB = [&](int T, int rg) {
#pragma unroll
        for (int u = 0; u < 4; u++) {
            const int rowblk = 2 * w + (u >> 1), kk = u & 1;
            const __bf16* gs = Wb + (size_t)(rowblk * 16 + srow) * K + T * 64 + kk * 32 + sch * 8;
            async16(&lds[rg * 24576 + 8192 + (w * 4 + u) * 512], gs);
        }
    };

    stgA(0, 0); stgB(0, 0);
    stgA(1, 1); stgB(1, 1);
    asm volatile("s_waitcnt vmcnt(6)" ::: "memory");
    asm volatile("s_barrier" ::: "memory");

    int rg = 0;
    for (int T = 0; T < 32; T++) {
        int rs = rg + 2; if (rs >= 3) rs -= 3;
        const int base = rg * 24576;
        bf16x8 fa[4], fb[4];

#pragma unroll
        for (int mi = 0; mi < 4; mi++)
            fa[mi] = *(const bf16x8*)&lds[base + ((wm * 4 + mi) * 2 + 0) * 512 + foff];
#pragma unroll
        for (int ni = 0; ni < 4; ni++)
            fb[ni] = *(const bf16x8*)&lds[base + 8192 + ((wn * 4 + ni) * 2 + 0) * 512 + foff];
        if (T < 30) stgA(T + 2, rs);
        asm volatile("s_barrier" ::: "memory");
        asm volatile("s_waitcnt lgkmcnt(0)" ::: "memory");
        __builtin_amdgcn_sched_barrier(0);
        __builtin_amdgcn_s_setprio(1);
#pragma unroll
        for (int mi = 0; mi < 4; mi++)
#pragma unroll
            for (int ni = 0; ni < 4; ni++)
                acc[mi][ni] = MFMA16(fa[mi], fb[ni], acc[mi][ni]);
        __builtin_amdgcn_s_setprio(0);
        asm volatile("s_barrier" ::: "memory");

#pragma unroll
        for (int mi = 0; mi < 4; mi++)
            fa[mi] = *(const bf16x8*)&lds[base + ((wm * 4 + mi) * 2 + 1) * 512 + foff];
#pragma unroll
        for (int ni = 0; ni < 4; ni++)
            fb[ni] = *(const bf16x8*)&lds[base + 8192 + ((wn * 4 + ni) * 2 + 1) * 512 + foff];
        if (T < 30) {
            stgB(T + 2, rs);
            asm volatile("s_waitcnt vmcnt(6)" ::: "memory");
        } else {
            asm volatile("s_waitcnt vmcnt(0)" ::: "memory");
        }
        asm volatile("s_barrier" ::: "memory");
        asm volatile("s_waitcnt lgkmcnt(0)" ::: "memory");
        __builtin_amdgcn_sched_barrier(0);
        __builtin_amdgcn_s_setprio(1);
#pragma unroll
        for (int mi = 0; mi < 4; mi++)
#pragma unroll
            for (int ni = 0; ni < 4; ni++)
                acc[mi][ni] = MFMA16(fa[mi], fb[ni], acc[mi][ni]);
        __builtin_amdgcn_s_setprio(0);
        asm volatile("s_barrier" ::: "memory");

        rg = (rg + 1 == 3) ? 0 : rg + 1;
    }

#pragma unroll
    for (int ni = 0; ni < 4; ni++) {
        const int col = n0 + wn * 64 + ni * 16 + c;
        const float bv = bias[col];
        const int h = col >> 7, dh = col & 127;
#pragma unroll
        for (int mi = 0; mi < 4; mi++) {
            const int rowb = m0 + wm * 64 + mi * 16 + g * 4;
#pragma unroll
            for (int r = 0; r < 4; r++) {
                const float v = acc[mi][ni][r] + bv;
                if (MODE == 0) {
                    ((float*)C0)[(size_t)(rowb + r) * 2048 + col] = v;
                } else {
                    const int lrow = (rowb + r) & 4095;
                    const int b = lrow >> 10, t = lrow & 1023;
                    if (seg == 0)
                        ((__bf16*)C0)[(((size_t)(b * 16 + h) * 1024) + t) * 128 + dh] = (__bf16)v;
                    else if (seg == 1)
                        C1[(((size_t)(b * 16 + h) * 2048) + 1024 + t) * 128 + dh] = v;
                    else
                        C2[(((size_t)(b * 16 + h) * 2048) + 1024 + t) * 128 + dh] = v;
                }
            }
        }
    }
}

// ---------------------------------------------------------------------------
// Flash attention: QBLK=32, 2 waves x 16 q-rows, 128-thread blocks,
// 2048 blocks = 8/CU (16 waves/CU). KVBLK=32. Wave-level compute
// (QK/softmax/PV, Kt/Vt/Pw layouts+swizzles) identical to verified r3.
// Dispatch: xcd=lin&7; j=lin>>3; bh=xcd*8+(j&7); qq=j>>3 (0..31);
//   c4=qq&3, m=qq>>2; qb = (m even) ? 4*c4+m/2 : 31-4*c4-m/2.
// Bijection onto 0..31; per-CU trip sum = 132 for every CU; one (b,h)/CU;
// 8 heads/XCD = 4MB K/V (L2-resident). trips = qb+1.
// ---------------------------------------------------------------------------
__global__ __launch_bounds__(128) void attn_k(const __bf16* __restrict__ Qw,
                                              const __bf16* __restrict__ cK,
                                              const __bf16* __restrict__ cV,
                                              __bf16* __restrict__ O) {
    __shared__ __bf16 Kt[32 * 128];     // 8 KB
    __shared__ u32 Vt32[128 * 16];      // 8 KB
    __shared__ __bf16 Pw[2][16 * 32];   // 2 KB

    const int tid = threadIdx.x;
    const int w = tid >> 6;             // 0..1
    const int lane = tid & 63;
    const int g = lane >> 4, c = lane & 15;

    const int lin = blockIdx.x + (blockIdx.y << 4) + (blockIdx.z << 8);
    const int xcd = lin & 7;
    const int j = lin >> 3;
    const int bh = xcd * 8 + (j & 7);
    const int qq = j >> 3;              // 0..31
    const int c4 = qq & 3, m = qq >> 2;
    const int qb = ((m & 1) == 0) ? (c4 * 4 + (m >> 1)) : (31 - c4 * 4 - (m >> 1));
    const int b = bh >> 4, h = bh & 15;
    const int q0 = qb << 5;
    const float inv_scale = 0.08838834764831845f; // 1/sqrt(128)

    const __bf16* qbase = Qw + (((size_t)bh * 1024) + q0 + w * 16) * 128;
    bf16x8 qf[4];
#pragma unroll
    for (int dc = 0; dc < 4; dc++)
        qf[dc] = *(const bf16x8*)&qbase[c * 128 + dc * 32 + g * 8];

    f32x4 accO[8] = {};
    float m_run[4], l_run[4];
#pragma unroll
    for (int r = 0; r < 4; r++) { m_run[r] = -1e30f; l_run[r] = 0.0f; }

    const int trips = qb + 1;
    const __bf16* kb = cK + (size_t)bh * 1024 * 128;
    const __bf16* vb = cV + (size_t)bh * 1024 * 128;

    // K staging (128 thr): thread owns key skey=tid>>2, chunks 4*(tid&3)..+3
    const int skey = tid >> 2, sgrp = tid & 3;
    const int ss = skey & 7;
    // V staging: thread owns key pair kp=tid>>3, dh block dbv=tid&7 (16 dh)
    const int kp = tid >> 3, dbv = tid & 7;

    for (int kt = 0; kt < trips; kt++) {
        const int k0 = kt * 32;
        // K: 4x bf16x8 (32 dh); V: 2 rows x 2x bf16x8 (16 dh each)
        const __bf16* kr = &kb[(size_t)(k0 + skey) * 128 + sgrp * 32];
        const bf16x8 k_a = *(const bf16x8*)&kr[0];
        const bf16x8 k_b = *(const bf16x8*)&kr[8];
        const bf16x8 k_c = *(const bf16x8*)&kr[16];
        const bf16x8 k_d = *(const bf16x8*)&kr[24];
        const __bf16* vr0 = &vb[(size_t)(k0 + 2 * kp) * 128 + dbv * 16];
        const __bf16* vr1 = &vb[(size_t)(k0 + 2 * kp + 1) * 128 + dbv * 16];
        const bf16x8 v0a = *(const bf16x8*)&vr0[0];
        const bf16x8 v0b = *(const bf16x8*)&vr0[8];
        const bf16x8 v1a = *(const bf16x8*)&vr1[0];
        const bf16x8 v1b = *(const bf16x8*)&vr1[8];
        __syncthreads();   // prior iteration's Kt/Vt reads complete
        {
            const int c0 = sgrp * 4;
            *(bf16x8*)&Kt[skey * 128 + (((c0 + 0) ^ ss) << 3)] = k_a;
            *(bf16x8*)&Kt[skey * 128 + (((c0 + 1) ^ ss) << 3)] = k_b;
            *(bf16x8*)&Kt[skey * 128 + (((c0 + 2) ^ ss) << 3)] = k_c;
            *(bf16x8*)&Kt[skey * 128 + (((c0 + 3) ^ ss) << 3)] = k_d;
        }
        {
            const u16x8 a0 = __builtin_bit_cast(u16x8, v0a);
            const u16x8 a1 = __builtin_bit_cast(u16x8, v0b);
            const u16x8 b0 = __builtin_bit_cast(u16x8, v1a);
            const u16x8 b1 = __builtin_bit_cast(u16x8, v1b);
#pragma unroll
            for (int jj = 0; jj < 8; jj++) {
                const int d0 = dbv * 16 + jj;
                const int d1 = dbv * 16 + 8 + jj;
                const int pc0 = (((kp >> 2) ^ ((d0 >> 3) & 3)) << 2) | (kp & 3);
                const int pc1 = (((kp >> 2) ^ ((d1 >> 3) & 3)) << 2) | (kp & 3);
                Vt32[d0 * 16 + pc0] = (u32)a0[jj] | ((u32)b0[jj] << 16);
                Vt32[d1 * 16 + pc1] = (u32)a1[jj] | ((u32)b1[jj] << 16);
            }
        }
        __syncthreads();   // staging visible

        // S = Q @ K^T  (two 16-key tiles)
        f32x4 s_acc[2] = {};
#pragma unroll
        for (int nt = 0; nt < 2; nt++) {
            const int krow = nt * 16 + c;
            const int ks = krow & 7;
#pragma unroll
            for (int dc = 0; dc < 4; dc++) {
                const bf16x8 kf =
                    *(const bf16x8*)&Kt[krow * 128 + (((dc * 4 + g) ^ ks) << 3)];
                s_acc[nt] = MFMA16(qf[dc], kf, s_acc[nt]);
            }
        }

        // mask + online softmax
        float p[2][4], alpha[4];
#pragma unroll
        for (int r = 0; r < 4; r++) {
            const int qrow = q0 + w * 16 + g * 4 + r;
            float s0 = (k0 + c      <= qrow) ? s_acc[0][r] * inv_scale : -1e30f;
            float s1 = (k0 + 16 + c <= qrow) ? s_acc[1][r] * inv_scale : -1e30f;
            float rm = fmaxf(s0, s1);
            rm = fmaxf(rm, __shfl_xor(rm, 1));
            rm = fmaxf(rm, __shfl_xor(rm, 2));
            rm = fmaxf(rm, __shfl_xor(rm, 4));
            rm = fmaxf(rm, __shfl_xor(rm, 8));
            const float mnew = fmaxf(m_run[r], rm);
            alpha[r] = __expf(m_run[r] - mnew);
            const float p0 = __expf(s0 - mnew);
            const float p1 = __expf(s1 - mnew);
            p[0][r] = p0; p[1][r] = p1;
            float ps = p0 + p1;
            ps += __shfl_xor(ps, 1);
            ps += __shfl_xor(ps, 2);
            ps += __shfl_xor(ps, 4);
            ps += __shfl_xor(ps, 8);
            l_run[r] = alpha[r] * l_run[r] + ps;
            m_run[r] = mnew;
        }
#pragma unroll
        for (int nt2 = 0; nt2 < 8; nt2++)
#pragma unroll
            for (int r = 0; r < 4; r++)
                accO[nt2][r] *= alpha[r];

        // P -> per-wave LDS (swizzled)
#pragma unroll
        for (int nt = 0; nt < 2; nt++)
#pragma unroll
            for (int r = 0; r < 4; r++)
                Pw[w][(g * 4 + r) * 32 + ((((nt << 1) | (c >> 3)) ^ g) << 3) + (c & 7)] =
                    (__bf16)p[nt][r];
        asm volatile("s_waitcnt lgkmcnt(0)" ::: "memory");
        __builtin_amdgcn_sched_barrier(0);

        const bf16x8 pf = *(const bf16x8*)&Pw[w][c * 32 + ((g ^ ((c >> 2) & 3)) << 3)];
#pragma unroll
        for (int nt2 = 0; nt2 < 8; nt2++) {
            const int vrow = nt2 * 16 + c;
            const bf16x8 vf = *(const bf16x8*)&(
                (const __bf16*)Vt32)[vrow * 32 + ((g ^ ((vrow >> 3) & 3)) << 3)];
            accO[nt2] = MFMA16(pf, vf, accO[nt2]);
        }
    }

    // epilogue: normalize, store bf16 to ws_attn [4096][2048]
#pragma unroll
    for (int nt2 = 0; nt2 < 8; nt2++)
#pragma unroll
        for (int r = 0; r < 4; r++) {
            const float v = accO[nt2][r] / l_run[r];
            const int row = b * 1024 + q0 + w * 16 + g * 4 + r;
            const int col = h * 128 + nt2 * 16 + c;
            O[(size_t)row * 2048 + col] = (__bf16)v;
        }
}

// ---------------------------------------------------------------------------
extern "C" void kernel_launch(void* const* d_in, const int* in_sizes, int n_in,
                              void* d_out, int out_size, void* d_ws, size_t ws_size,
                              hipStream_t stream) {
    const float* query       = (const float*)d_in[0];
    const float* key         = (const float*)d_in[1];
    const float* value       = (const float*)d_in[2];
    const float* cache_key   = (const float*)d_in[3];
    const float* cache_value = (const float*)d_in[4];
    const float* Wq = (const float*)d_in[5];
    const float* bq = (const float*)d_in[6];
    const float* Wk = (const float*)d_in[7];
    const float* bk = (const float*)d_in[8];
    const float* Wv = (const float*)d_in[9];
    const float* bv = (const float*)d_in[10];
    const float* Wo = (const float*)d_in[11];
    const float* bo = (const float*)d_in[12];

    float* out   = (float*)d_out;              // [4096][2048] fp32
    float* new_k = out + 8388608;              // [B][H][2048][128] fp32
    float* new_v = out + 25165824;

    // workspace (bf16 elems): q_bf/k_bf/v_bf MUST be contiguous (A-concat)
    __bf16* p = (__bf16*)d_ws;
    __bf16* ws_q    = p; p += 8388608;         // [b][h][1024][128]
    __bf16* ws_attn = p; p += 8388608;         // [4096][2048]
    __bf16* q_bf    = p; p += 8388608;         // A-concat rows 0..4095
    __bf16* k_bf    = p; p += 8388608;         //               4096..8191
    __bf16* v_bf    = p; p += 8388608;         //               8192..12287
    __bf16* wq_bf   = p; p += 4194304;
    __bf16* wk_bf   = p; p += 4194304;
    __bf16* wv_bf   = p; p += 4194304;
    __bf16* wo_bf   = p; p += 4194304;
    __bf16* ck_bf   = p; p += 8388608;         // [b][h][1024][128] head-major
    __bf16* cv_bf   = p;

    static bool s_attr = false;
    if (!s_attr) {
        hipFuncSetAttribute(reinterpret_cast<const void*>(&gemm8<1>),
                            hipFuncAttributeMaxDynamicSharedMemorySize, 147456);
        hipFuncSetAttribute(reinterpret_cast<const void*>(&gemm8<0>),
                            hipFuncAttributeMaxDynamicSharedMemorySize, 147456);
        s_attr = true;
    }

    prep<<<4096, 256, 0, stream>>>(query, key, value, Wq, Wk, Wv, Wo,
                                   cache_key, cache_value, new_k, new_v,
                                   q_bf, k_bf, v_bf, wq_bf, wk_bf, wv_bf, wo_bf,
                                   ck_bf, cv_bf);
    gemm8<1><<<768, 512, 147456, stream>>>(q_bf, wq_bf, wk_bf, wv_bf,
                                           bq, bk, bv, ws_q, new_k, new_v);
    attn_k<<<dim3(16, 16, 8), 128, 0, stream>>>(ws_q, ck_bf, cv_bf, ws_attn);
    gemm8<0><<<256, 512, 147456, stream>>>(ws_attn, wo_bf, nullptr, nullptr,
                                           bo, nullptr, nullptr, out, nullptr, nullptr);
}